// Round 4
// baseline (221.086 us; speedup 1.0000x reference)
//
#include <hip/hip_runtime.h>

typedef short short4v __attribute__((ext_vector_type(4)));
typedef short short8v __attribute__((ext_vector_type(8)));
typedef float float4v __attribute__((ext_vector_type(4)));
typedef unsigned short u16;

#define NB 2
#define NL 2048
#define NS 2048
#define NH 8
#define NE 64
#define HE (NH*NE)    // 512
#define NLT (NL/64)   // 32 l-tiles per (b,h)
#define NST (NS/64)   // 32 s-tiles
#define TILE_U16 4096 // one 64x64 bf16 tile image = 8 KB

// pack two fp32 -> dword of two bf16 (round-to-nearest, half-up)
static __device__ __forceinline__ unsigned pk2bf(float a, float b) {
  union { float f; unsigned u; } x, y; x.f = a; y.f = b;
  return __builtin_amdgcn_perm(y.u + 0x8000u, x.u + 0x8000u, 0x07060302u);
}

// single-instruction pack: low16 = bf16(a), high16 = bf16(b), RTNE
static __device__ __forceinline__ unsigned cvtpk(float a, float b) {
  unsigned r;
  asm("v_cvt_pk_bf16_f32 %0, %1, %2" : "=v"(r) : "v"(a), "v"(b));
  return r;
}

// single-instruction 2^x
static __device__ __forceinline__ float fexp2(float x) {
  float r;
  asm("v_exp_f32 %0, %1" : "=v"(r) : "v"(x));
  return r;
}

#define GLD16(gp, lp) __builtin_amdgcn_global_load_lds( \
    (const __attribute__((address_space(1))) void*)(gp), \
    (__attribute__((address_space(3))) void*)(lp), 16, 0, 0)

// K-image swizzle hash: uses s bits {0,1,3} so the permuted QK row set
// (s = 8*(ln15>>2) + (ln15&3) + 4*pair + 32*sl) keeps the same hash:
// +4*pair only touches bit 2, +32*sl only bit 5.
static __device__ __forceinline__ int fK(int s) { return (s & 3) | ((s >> 1) & 4); }

// ---------------------------------------------------------------------------
// Pre-pass: K,V fp32 -> bf16 tile images in d_ws, in the EXACT swizzled byte
// order the main kernel's LDS wants (K row-major, V transposed). K and V in
// separate blocks (1024 WGs, 4/CU) for latency overlap.
// ---------------------------------------------------------------------------
__global__ __launch_bounds__(256)
void prepack(const float* __restrict__ kp, const float* __restrict__ vp,
             u16* __restrict__ kimg, u16* __restrict__ vimg)
{
  __shared__ __align__(16) u16 ldsv[TILE_U16];

  const int bid  = blockIdx.x;          // 0..1023
  const int tile = bid >> 1;            // bh*NST + st
  const int doV  = bid & 1;
  const int st = tile & (NST - 1);
  const int bh = tile >> 5;
  const int h  = bh & (NH - 1);
  const int b  = bh >> 3;
  const int s0 = st * 64;
  const size_t base = (size_t)b * NS * HE + h * NE;
  const int tid  = threadIdx.x;
  const int wv   = tid >> 6;
  const int lane = tid & 63;
  const int ln7  = lane & 7;

  if (!doV) {
    u16* kt = kimg + (size_t)tile * TILE_U16;
    for (int slot = tid; slot < 512; slot += 256) {
      const int srow = slot >> 3, p = slot & 7, c = p ^ fK(srow);
      const float* src = kp + base + (size_t)(s0 + srow) * HE + c * 8;
      float4 x0 = *(const float4*)src;
      float4 x1 = *(const float4*)(src + 4);
      unsigned d[4] = { pk2bf(x0.x, x0.y), pk2bf(x0.z, x0.w),
                        pk2bf(x1.x, x1.y), pk2bf(x1.z, x1.w) };
      *(int4*)(kt + slot * 8) = *(const int4*)d;
    }
    return;
  }

  u16* vt = vimg + (size_t)tile * TILE_U16;
  {
    const float* vcol = vp + base + (size_t)(s0 + wv * 16) * HE + lane;
    unsigned vr[8];
    #pragma unroll
    for (int jj = 0; jj < 8; ++jj)
      vr[jj] = pk2bf(vcol[(size_t)(2 * jj) * HE], vcol[(size_t)(2 * jj + 1) * HE]);
    #pragma unroll
    for (int i = 0; i < 2; ++i) {
      const int cs = (2 * wv + i) ^ ln7;
      int4 t4 = make_int4((int)vr[4*i+0], (int)vr[4*i+1],
                          (int)vr[4*i+2], (int)vr[4*i+3]);
      *(int4*)(&ldsv[lane * 64 + cs * 8]) = t4;
    }
  }
  __syncthreads();
  {
    const int4* s = (const int4*)ldsv;
    int4* dst = (int4*)vt;
    dst[tid]       = s[tid];
    dst[tid + 256] = s[tid + 256];
  }
}

// ---------------------------------------------------------------------------
// Main. 8 waves = 2 streams (even/odd s-tiles) x 2 s-halves x 2 l-halves.
// Each wave: 32s x 32l scores/tile -> reads only its s-half of K and V
// (8 ds_read_b128/tile/wave, half of the R2 structure). Hardened rebuild of
// the failed R3: plain __syncthreads() in the main loop (compiler-visible
// vmcnt+lgkm drain), char-based LDS overlay, named fragment temporaries,
// and an atomicAdd (ds_add_f32) epilogue with canonical row addressing.
// ---------------------------------------------------------------------------
__global__ __launch_bounds__(512, 4)
void assa_fwd(const float* __restrict__ qp, const u16* __restrict__ kimg,
              const u16* __restrict__ vimg, const float* __restrict__ a1p,
              const float* __restrict__ a2p, float* __restrict__ op)
{
  // [strm*2 + buf] tile slots of 16 KB (K|V), reused as f32 scratch at the end
  __shared__ __align__(16) unsigned char lds_raw[65536];
  u16* ldsb = (u16*)lds_raw;

  const int tid  = threadIdx.x;
  const int wv   = tid >> 6;        // 0..7
  const int ws   = wv & 3;          // role within stream
  const int strm = wv >> 2;         // 0: even s-tiles, 1: odd s-tiles
  const int sl   = ws >> 1;         // s-half within tile (32 rows)
  const int lg   = ws & 1;          // l-half (32 rows)
  const int lane = tid & 63;
  const int ln15 = lane & 15;
  const int ln7  = lane & 7;
  const int quad = lane >> 4;

  // XCD swizzle: all 32 l-tiles of one (b,h) on one XCD
  const int bid = blockIdx.x;
  const int bh  = bid & 15;
  const int lt  = bid >> 4;
  const int h   = bh & (NH - 1);
  const int b   = bh >> 3;

  const int lbase = lt * 64 + lg * 32;

  // Q B-fragments for the wave's 32 l rows (two 16-row groups), pre-scaled by
  // (1/sqrt(64)) * log2(e) so the dense branch is a bare v_exp_f32 (exp2).
  short8v qf00, qf01, qf10, qf11;   // qf<l16><echunk>
  {
    const float qs = 0.125f * 1.44269504089f;
    const float* qr0 = qp + ((size_t)(b * NL + lbase + ln15)) * HE + h * NE + quad * 8;
    float4 a0 = *(const float4*)(qr0);
    float4 a1 = *(const float4*)(qr0 + 4);
    float4 a2 = *(const float4*)(qr0 + 32);
    float4 a3 = *(const float4*)(qr0 + 36);
    unsigned d0[4] = { pk2bf(qs*a0.x, qs*a0.y), pk2bf(qs*a0.z, qs*a0.w),
                       pk2bf(qs*a1.x, qs*a1.y), pk2bf(qs*a1.z, qs*a1.w) };
    unsigned d1[4] = { pk2bf(qs*a2.x, qs*a2.y), pk2bf(qs*a2.z, qs*a2.w),
                       pk2bf(qs*a3.x, qs*a3.y), pk2bf(qs*a3.z, qs*a3.w) };
    qf00 = *(const short8v*)d0;
    qf01 = *(const short8v*)d1;
    const float* qr1 = qr0 + (size_t)16 * HE;
    float4 b0 = *(const float4*)(qr1);
    float4 b1 = *(const float4*)(qr1 + 4);
    float4 b2 = *(const float4*)(qr1 + 32);
    float4 b3 = *(const float4*)(qr1 + 36);
    unsigned e0[4] = { pk2bf(qs*b0.x, qs*b0.y), pk2bf(qs*b0.z, qs*b0.w),
                       pk2bf(qs*b1.x, qs*b1.y), pk2bf(qs*b1.z, qs*b1.w) };
    unsigned e1[4] = { pk2bf(qs*b2.x, qs*b2.y), pk2bf(qs*b2.z, qs*b2.w),
                       pk2bf(qs*b3.x, qs*b3.y), pk2bf(qs*b3.z, qs*b3.w) };
    qf10 = *(const short8v*)e0;
    qf11 = *(const short8v*)e1;
  }

  // ones B-fragment (bf16 1.0) for the denominator MFMA
  short8v ones8;
  #pragma unroll
  for (int j = 0; j < 8; ++j) ones8[j] = (short)0x3F80;

  const size_t tbase = (size_t)bh * NST;

  float4v acc_s[2][4], acc_d[2][4], acc_l[2];
  #pragma unroll
  for (int g = 0; g < 2; ++g) {
    #pragma unroll
    for (int t = 0; t < 4; ++t)
      #pragma unroll
      for (int r = 0; r < 4; ++r) { acc_s[g][t][r] = 0.0f; acc_d[g][t][r] = 0.0f; }
    #pragma unroll
    for (int r = 0; r < 4; ++r) acc_l[g][r] = 0.0f;
  }

  // DMA one tile (16 KB) into this stream's buffer nb:
  // ws 0,1 -> K image halves, ws 2,3 -> V. 4 global_load_lds per wave.
  auto dma_tile = [&](int st, int nb) {
    const int hf = ws & 1;
    u16* base = ldsb + (strm * 2 + nb) * (2 * TILE_U16);
    const u16* g;
    u16* l;
    if (ws < 2) {
      g = kimg + (tbase + st) * TILE_U16 + hf * 2048 + lane * 8;
      l = base + hf * 2048;
    } else {
      g = vimg + (tbase + st) * TILE_U16 + hf * 2048 + lane * 8;
      l = base + TILE_U16 + hf * 2048;
    }
    GLD16(g,        l);
    GLD16(g +  512, l +  512);
    GLD16(g + 1024, l + 1024);
    GLD16(g + 1536, l + 1536);
  };

  dma_tile(strm, 0);   // stream's first tile (st = strm)

  const int rperm = 8 * (ln15 >> 2) + (ln15 & 3);          // + 32*sl + 4*pair
  const int fk    = (ln15 & 3) | (((ln15 >> 2) & 1) << 2); // fK of that row

  for (int it = 0; it < NST / 2; ++it) {
    // __syncthreads drains own vmcnt (prefetched tile) + lgkm, then barriers
    __syncthreads();
    if (it + 1 < NST / 2) dma_tile(2 * (it + 1) + strm, (it + 1) & 1);

    const u16* kb_l = ldsb + (strm * 2 + (it & 1)) * (2 * TILE_U16);
    const u16* vb_l = kb_l + TILE_U16;

    // ---- QK^T: 32s (own half) x 32l ----
    const u16* krow0 = &kb_l[(32 * sl + rperm) * 64];      // pair 0
    const u16* krow1 = krow0 + 4 * 64;                     // pair 1 (+4 rows)
    short8v ka0 = *(const short8v*)(krow0 + (quad ^ fk) * 8);
    short8v ka1 = *(const short8v*)(krow0 + ((4 + quad) ^ fk) * 8);
    short8v kb0 = *(const short8v*)(krow1 + (quad ^ fk) * 8);
    short8v kb1 = *(const short8v*)(krow1 + ((4 + quad) ^ fk) * 8);

    float4v z00, z01, z10, z11;   // z<pair><l16>
    #pragma unroll
    for (int r = 0; r < 4; ++r) { z00[r] = 0.0f; z01[r] = 0.0f; z10[r] = 0.0f; z11[r] = 0.0f; }
    __builtin_amdgcn_s_setprio(1);
    z00 = __builtin_amdgcn_mfma_f32_16x16x32_bf16(ka0, qf00, z00, 0, 0, 0);
    z00 = __builtin_amdgcn_mfma_f32_16x16x32_bf16(ka1, qf01, z00, 0, 0, 0);
    z01 = __builtin_amdgcn_mfma_f32_16x16x32_bf16(ka0, qf10, z01, 0, 0, 0);
    z01 = __builtin_amdgcn_mfma_f32_16x16x32_bf16(ka1, qf11, z01, 0, 0, 0);
    z10 = __builtin_amdgcn_mfma_f32_16x16x32_bf16(kb0, qf00, z10, 0, 0, 0);
    z10 = __builtin_amdgcn_mfma_f32_16x16x32_bf16(kb1, qf01, z10, 0, 0, 0);
    z11 = __builtin_amdgcn_mfma_f32_16x16x32_bf16(kb0, qf10, z11, 0, 0, 0);
    z11 = __builtin_amdgcn_mfma_f32_16x16x32_bf16(kb1, qf11, z11, 0, 0, 0);
    __builtin_amdgcn_s_setprio(0);
    // lane (quad,ln15): z<p><g>[r] = score'[s = 32sl + 8quad + 4p + r]
    //                                       [l = lg*32 + g*16 + ln15]

    // ---- in-register relu^2 / exp2 -> bf16 P fragments (per l16 group) ----
    short8v as8_0, ad8_0, as8_1, ad8_1;
    {
      float ps[8], pd[8];
      #pragma unroll
      for (int r = 0; r < 4; ++r) {
        float s0 = z00[r], s1 = z10[r];
        float r0 = s0 > 0.0f ? s0 : 0.0f;
        float r1 = s1 > 0.0f ? s1 : 0.0f;
        ps[r] = r0 * r0;  ps[4 + r] = r1 * r1;    // (log2e)^2 * relu(s)^2
        pd[r] = fexp2(s0); pd[4 + r] = fexp2(s1); // exp(s)
      }
      unsigned da[4] = { cvtpk(ps[0], ps[1]), cvtpk(ps[2], ps[3]),
                         cvtpk(ps[4], ps[5]), cvtpk(ps[6], ps[7]) };
      unsigned db[4] = { cvtpk(pd[0], pd[1]), cvtpk(pd[2], pd[3]),
                         cvtpk(pd[4], pd[5]), cvtpk(pd[6], pd[7]) };
      as8_0 = *(const short8v*)da;
      ad8_0 = *(const short8v*)db;
    }
    {
      float ps[8], pd[8];
      #pragma unroll
      for (int r = 0; r < 4; ++r) {
        float s0 = z01[r], s1 = z11[r];
        float r0 = s0 > 0.0f ? s0 : 0.0f;
        float r1 = s1 > 0.0f ? s1 : 0.0f;
        ps[r] = r0 * r0;  ps[4 + r] = r1 * r1;
        pd[r] = fexp2(s0); pd[4 + r] = fexp2(s1);
      }
      unsigned da[4] = { cvtpk(ps[0], ps[1]), cvtpk(ps[2], ps[3]),
                         cvtpk(ps[4], ps[5]), cvtpk(ps[6], ps[7]) };
      unsigned db[4] = { cvtpk(pd[0], pd[1]), cvtpk(pd[2], pd[3]),
                         cvtpk(pd[4], pd[5]), cvtpk(pd[6], pd[7]) };
      as8_1 = *(const short8v*)da;
      ad8_1 = *(const short8v*)db;
    }

    // denominators on the matrix pipe (C rows aligned with PV C rows)
    acc_l[0] = __builtin_amdgcn_mfma_f32_16x16x32_bf16(ad8_0, ones8, acc_l[0], 0, 0, 0);
    acc_l[1] = __builtin_amdgcn_mfma_f32_16x16x32_bf16(ad8_1, ones8, acc_l[1], 0, 0, 0);

    // ---- PV: V fragments for own s-half, shared across both l-groups ----
    __builtin_amdgcn_s_setprio(1);
    #pragma unroll
    for (int t = 0; t < 4; ++t) {
      short8v vf = *(const short8v*)(&vb_l[(t * 16 + ln15) * 64 +
                      (((4 * sl + quad) ^ ln7) * 8)]);
      acc_s[0][t] = __builtin_amdgcn_mfma_f32_16x16x32_bf16(as8_0, vf, acc_s[0][t], 0, 0, 0);
      acc_d[0][t] = __builtin_amdgcn_mfma_f32_16x16x32_bf16(ad8_0, vf, acc_d[0][t], 0, 0, 0);
      acc_s[1][t] = __builtin_amdgcn_mfma_f32_16x16x32_bf16(as8_1, vf, acc_s[1][t], 0, 0, 0);
      acc_d[1][t] = __builtin_amdgcn_mfma_f32_16x16x32_bf16(ad8_1, vf, acc_d[1][t], 0, 0, 0);
    }
    __builtin_amdgcn_s_setprio(0);
  }

  // ---- combine the 4 partials per l-half via LDS atomics ------------------
  // Canonical rows (per lg block of 72): 0..31 acc_s, 32..63 acc_d, 64..71
  // acc_l. Cell (row, lane) always holds the C element for l-row
  // (lane>>4)*4+r, so writer lane == reader lane.
  __syncthreads();   // all tile reads done -> lds_raw reusable as f32 scratch
  float* red = (float*)lds_raw;
  for (int i = tid; i < 144 * 64; i += 512) red[i] = 0.0f;
  __syncthreads();
  {
    const int rb = lg * 72;
    #pragma unroll
    for (int l16 = 0; l16 < 2; ++l16) {
      #pragma unroll
      for (int t = 0; t < 4; ++t)
        #pragma unroll
        for (int r = 0; r < 4; ++r) {
          atomicAdd(&red[(rb + l16 * 16 + t * 4 + r) * 64 + lane], acc_s[l16][t][r]);
          atomicAdd(&red[(rb + 32 + l16 * 16 + t * 4 + r) * 64 + lane], acc_d[l16][t][r]);
        }
      #pragma unroll
      for (int r = 0; r < 4; ++r)
        atomicAdd(&red[(rb + 64 + l16 * 4 + r) * 64 + lane], acc_l[l16][r]);
    }
  }
  __syncthreads();

  if (wv < 2) {       // wv0 (lg=0) and wv1 (lg=1) write the final output
    const float w1 = __expf(a1p[0]), w2 = __expf(a2p[0]);
    // fold the (log2 e)^2 from the pre-scaled scores out of the sparse branch
    const float al1 = (w1 / (w1 + w2)) * 0.48045301391820142f; // (ln 2)^2
    const float al2 = w2 / (w1 + w2);
    const int rb = lg * 72;

    #pragma unroll
    for (int l16 = 0; l16 < 2; ++l16) {
      float inv[4];
      #pragma unroll
      for (int r = 0; r < 4; ++r)
        inv[r] = al2 / red[(rb + 64 + l16 * 4 + r) * 64 + lane];
      #pragma unroll
      for (int t = 0; t < 4; ++t)
        #pragma unroll
        for (int r = 0; r < 4; ++r) {
          const int idx = l16 * 16 + t * 4 + r;
          float val = al1 * red[(rb + idx) * 64 + lane]
                    + inv[r] * red[(rb + 32 + idx) * 64 + lane];
          const int l = lbase + l16 * 16 + quad * 4 + r;
          const int e = t * 16 + ln15;
          op[((size_t)(b * NL + l)) * HE + h * NE + e] = val;
        }
    }
  }
}

extern "C" void kernel_launch(void* const* d_in, const int* in_sizes, int n_in,
                              void* d_out, int out_size, void* d_ws, size_t ws_size,
                              hipStream_t stream) {
  const float* q  = (const float*)d_in[0];
  const float* k  = (const float*)d_in[1];
  const float* v  = (const float*)d_in[2];
  const float* a1 = (const float*)d_in[3];
  const float* a2 = (const float*)d_in[4];
  float* out = (float*)d_out;
  (void)in_sizes; (void)n_in; (void)out_size; (void)ws_size;

  u16* kimg = (u16*)d_ws;                                   // 4 MiB
  u16* vimg = kimg + (size_t)NB * NH * NST * TILE_U16;      // 4 MiB

  prepack<<<dim3(NB * NH * NST * 2), dim3(256), 0, stream>>>(k, v, kimg, vimg);
  assa_fwd<<<dim3(NB * NH * NLT), dim3(512), 0, stream>>>(q, kimg, vimg, a1, a2, out);
}

// Round 6
// 107.178 us; speedup vs baseline: 2.0628x; 2.0628x over previous
//
#include <hip/hip_runtime.h>

typedef short short4v __attribute__((ext_vector_type(4)));
typedef short short8v __attribute__((ext_vector_type(8)));
typedef float float4v __attribute__((ext_vector_type(4)));
typedef unsigned short u16;

#define NB 2
#define NL 2048
#define NS 2048
#define NH 8
#define NE 64
#define HE (NH*NE)    // 512
#define NLT (NL/64)   // 32 l-tiles per (b,h)
#define NST (NS/64)   // 32 s-tiles
#define TILE_U16 4096 // one 64x64 bf16 tile image = 8 KB

// pack two fp32 -> dword of two bf16 (round-to-nearest, half-up)
static __device__ __forceinline__ unsigned pk2bf(float a, float b) {
  union { float f; unsigned u; } x, y; x.f = a; y.f = b;
  return __builtin_amdgcn_perm(y.u + 0x8000u, x.u + 0x8000u, 0x07060302u);
}

// single-instruction pack: low16 = bf16(a), high16 = bf16(b), RTNE
static __device__ __forceinline__ unsigned cvtpk(float a, float b) {
  unsigned r;
  asm("v_cvt_pk_bf16_f32 %0, %1, %2" : "=v"(r) : "v"(a), "v"(b));
  return r;
}

// single-instruction 2^x
static __device__ __forceinline__ float fexp2(float x) {
  float r;
  asm("v_exp_f32 %0, %1" : "=v"(r) : "v"(x));
  return r;
}

#define GLD16(gp, lp) __builtin_amdgcn_global_load_lds( \
    (const __attribute__((address_space(1))) void*)(gp), \
    (__attribute__((address_space(3))) void*)(lp), 16, 0, 0)

// K-image swizzle hash: uses s bits {0,1,3} so the permuted QK row set
// (s = 8*(ln15>>2) + (ln15&3) + 4c) still spans all 8 chunk slots.
static __device__ __forceinline__ int fK(int s) { return (s & 3) | ((s >> 1) & 4); }

// ---------------------------------------------------------------------------
// Pre-pass: K,V fp32 -> bf16 tile images in d_ws, in the EXACT swizzled byte
// order the main kernel's LDS wants (K row-major, V transposed). K and V in
// separate blocks (1024 WGs, 4/CU) for latency overlap.
// ---------------------------------------------------------------------------
__global__ __launch_bounds__(256)
void prepack(const float* __restrict__ kp, const float* __restrict__ vp,
             u16* __restrict__ kimg, u16* __restrict__ vimg)
{
  __shared__ __align__(16) u16 ldsv[TILE_U16];

  const int bid  = blockIdx.x;          // 0..1023
  const int tile = bid >> 1;            // bh*NST + st
  const int doV  = bid & 1;
  const int st = tile & (NST - 1);
  const int bh = tile >> 5;
  const int h  = bh & (NH - 1);
  const int b  = bh >> 3;
  const int s0 = st * 64;
  const size_t base = (size_t)b * NS * HE + h * NE;
  const int tid  = threadIdx.x;
  const int wv   = tid >> 6;
  const int lane = tid & 63;
  const int ln7  = lane & 7;

  if (!doV) {
    u16* kt = kimg + (size_t)tile * TILE_U16;
    for (int slot = tid; slot < 512; slot += 256) {
      const int srow = slot >> 3, p = slot & 7, c = p ^ fK(srow);
      const float* src = kp + base + (size_t)(s0 + srow) * HE + c * 8;
      float4 x0 = *(const float4*)src;
      float4 x1 = *(const float4*)(src + 4);
      unsigned d[4] = { pk2bf(x0.x, x0.y), pk2bf(x0.z, x0.w),
                        pk2bf(x1.x, x1.y), pk2bf(x1.z, x1.w) };
      *(int4*)(kt + slot * 8) = *(const int4*)d;
    }
    return;
  }

  u16* vt = vimg + (size_t)tile * TILE_U16;
  {
    const float* vcol = vp + base + (size_t)(s0 + wv * 16) * HE + lane;
    unsigned vr[8];
    #pragma unroll
    for (int jj = 0; jj < 8; ++jj)
      vr[jj] = pk2bf(vcol[(size_t)(2 * jj) * HE], vcol[(size_t)(2 * jj + 1) * HE]);
    #pragma unroll
    for (int i = 0; i < 2; ++i) {
      const int cs = (2 * wv + i) ^ ln7;
      int4 t4 = make_int4((int)vr[4*i+0], (int)vr[4*i+1],
                          (int)vr[4*i+2], (int)vr[4*i+3]);
      *(int4*)(&ldsv[lane * 64 + cs * 8]) = t4;
    }
  }
  __syncthreads();
  {
    const int4* s = (const int4*)ldsv;
    int4* dst = (int4*)vt;
    dst[tid]       = s[tid];
    dst[tid + 256] = s[tid + 256];
  }
}

// ---------------------------------------------------------------------------
// Main (R2-verified structure). In-block S-split for occupancy:
//   - 512-thread WG (8 waves), grid 512 WGs (2/CU): waves 0-3 sweep EVEN
//     s-tiles, waves 4-7 sweep ODD s-tiles -> 16 waves/CU (4 waves/SIMD).
//   - per-stream double-buffered LDS: [stream][buf][K|V] = 64 KB/block.
//   - partial acc (incl. softmax denominator, which is linear) combined
//     once at the end via LDS, column-major scalar layout (conflict-free).
//   - VALU cuts: Q pre-scaled by 0.125*log2(e) -> dense branch is a bare
//     v_exp_f32 (exp2); relu^2 branch is degree-2 homogeneous so the
//     (log2 e)^2 factor folds into alpha1 at the epilogue. P-matrix bf16
//     packs use 1-op v_cvt_pk_bf16_f32.
// THIS ROUND's single change: __launch_bounds__(512,4) -> (512,2).
// Arg2 is min BLOCKS/CU (CUDA semantics, proven by R4's VGPR_Count=64 at
// (512,4): 4 blk x 8 waves = 8 waves/SIMD -> 64-reg cap -> spills). (512,2)
// = 16 waves/CU -> 128-reg cap >= the ~95-reg working set -> no spill; LDS
// (64 KB) independently limits to the same 2 blocks/CU, so occupancy is
// unchanged and only the spilling goes away.
// ---------------------------------------------------------------------------
__global__ __launch_bounds__(512, 2)
void assa_fwd(const float* __restrict__ qp, const u16* __restrict__ kimg,
              const u16* __restrict__ vimg, const float* __restrict__ a1p,
              const float* __restrict__ a2p, float* __restrict__ op)
{
  __shared__ __align__(16) u16 ldsb[2][2][2 * TILE_U16];  // [strm][buf][K|V] 64KB

  const int tid  = threadIdx.x;
  const int wv   = tid >> 6;        // 0..7
  const int ws   = wv & 3;          // l-group / dma role within stream
  const int strm = wv >> 2;         // 0: even s-tiles, 1: odd s-tiles
  const int lane = tid & 63;
  const int ln15 = lane & 15;
  const int ln7  = lane & 7;
  const int quad = lane >> 4;

  // XCD swizzle: all 32 l-tiles of one (b,h) on one XCD
  const int bid = blockIdx.x;
  const int bh  = bid & 15;
  const int lt  = bid >> 4;
  const int h   = bh & (NH - 1);
  const int b   = bh >> 3;

  const int lbase = lt * 64 + ws * 16;

  // Q B-fragments, pre-scaled by (1/sqrt(64)) * log2(e) so the dense branch
  // can use exp2 directly.
  short8v qf0, qf1;
  {
    const float qs = 0.125f * 1.44269504089f;
    const float* qrow = qp + ((size_t)(b * NL + lbase + ln15)) * HE + h * NE + quad * 8;
    float4 q0 = *(const float4*)(qrow);
    float4 q1 = *(const float4*)(qrow + 4);
    float4 q2 = *(const float4*)(qrow + 32);
    float4 q3 = *(const float4*)(qrow + 36);
    unsigned d0[4] = { pk2bf(qs*q0.x, qs*q0.y), pk2bf(qs*q0.z, qs*q0.w),
                       pk2bf(qs*q1.x, qs*q1.y), pk2bf(qs*q1.z, qs*q1.w) };
    unsigned d1[4] = { pk2bf(qs*q2.x, qs*q2.y), pk2bf(qs*q2.z, qs*q2.w),
                       pk2bf(qs*q3.x, qs*q3.y), pk2bf(qs*q3.z, qs*q3.w) };
    qf0 = *(const short8v*)d0;
    qf1 = *(const short8v*)d1;
  }

  // ones B-fragment (bf16 1.0 in every slot) for the denominator MFMA
  short8v ones8;
  #pragma unroll
  for (int j = 0; j < 8; ++j) ones8[j] = (short)0x3F80;

  const size_t tbase = (size_t)bh * NST;

  float4v acc_s[4], acc_d[4], acc_l;
  #pragma unroll
  for (int t = 0; t < 4; ++t)
    #pragma unroll
    for (int r = 0; r < 4; ++r) { acc_s[t][r] = 0.0f; acc_d[t][r] = 0.0f; }
  #pragma unroll
  for (int r = 0; r < 4; ++r) acc_l[r] = 0.0f;

  // DMA one tile (16 KB) into this stream's buffer nb:
  // ws 0,1 -> K image halves, ws 2,3 -> V. 4 global_load_lds per wave.
  auto dma_tile = [&](int st, int nb) {
    const int hf = ws & 1;
    const u16* g;
    u16* l;
    if (ws < 2) {
      g = kimg + (tbase + st) * TILE_U16 + hf * 2048 + lane * 8;
      l = &ldsb[strm][nb][hf * 2048];
    } else {
      g = vimg + (tbase + st) * TILE_U16 + hf * 2048 + lane * 8;
      l = &ldsb[strm][nb][TILE_U16 + hf * 2048];
    }
    GLD16(g,        l);
    GLD16(g +  512, l +  512);
    GLD16(g + 1024, l + 1024);
    GLD16(g + 1536, l + 1536);
  };

  dma_tile(strm, 0);   // stream's first tile (st = strm)

  const int rperm = 8 * (ln15 >> 2) + (ln15 & 3);          // + 32U + 4c
  const int fk    = (ln15 & 3) | (((ln15 >> 2) & 1) << 2); // fK of that row

  for (int it = 0; it < NST / 2; ++it) {
    asm volatile("s_waitcnt vmcnt(0)" ::: "memory");
    __builtin_amdgcn_s_barrier();
    asm volatile("" ::: "memory");  // keep DMA issue / LDS reads below barrier
    if (it + 1 < NST / 2) dma_tile(2 * (it + 1) + strm, (it + 1) & 1);

    const u16* kb_l = ldsb[strm][it & 1];
    const u16* vb_l = kb_l + TILE_U16;

    #pragma unroll
    for (int U = 0; U < 2; ++U) {
      float4v sa0, sa1;
      #pragma unroll
      for (int r = 0; r < 4; ++r) { sa0[r] = 0.0f; sa1[r] = 0.0f; }
      const u16* krow0 = &kb_l[(32 * U + rperm) * 64];
      const u16* krow1 = krow0 + 4 * 64;
      short8v kf00 = *(const short8v*)(krow0 + (quad ^ fk) * 8);
      short8v kf01 = *(const short8v*)(krow0 + ((4 + quad) ^ fk) * 8);
      short8v kf10 = *(const short8v*)(krow1 + (quad ^ fk) * 8);
      short8v kf11 = *(const short8v*)(krow1 + ((4 + quad) ^ fk) * 8);
      __builtin_amdgcn_s_setprio(1);
      sa0 = __builtin_amdgcn_mfma_f32_16x16x32_bf16(kf00, qf0, sa0, 0, 0, 0);
      sa0 = __builtin_amdgcn_mfma_f32_16x16x32_bf16(kf01, qf1, sa0, 0, 0, 0);
      sa1 = __builtin_amdgcn_mfma_f32_16x16x32_bf16(kf10, qf0, sa1, 0, 0, 0);
      sa1 = __builtin_amdgcn_mfma_f32_16x16x32_bf16(kf11, qf1, sa1, 0, 0, 0);
      __builtin_amdgcn_s_setprio(0);
      // lane (quad,l=ln15): sa0[r] = score'[s=32U+8q+r][l], sa1[r] = +4
      // where score' = score * log2(e)

      float ps[8], pd[8];
      #pragma unroll
      for (int r = 0; r < 4; ++r) {
        float s0 = sa0[r], s1 = sa1[r];
        float r0 = s0 > 0.0f ? s0 : 0.0f;
        float r1 = s1 > 0.0f ? s1 : 0.0f;
        ps[r] = r0 * r0;  ps[4 + r] = r1 * r1;   // = (log2e)^2 * relu(s)^2
        pd[r] = fexp2(s0); pd[4 + r] = fexp2(s1); // = exp(s)
      }
      unsigned da[4] = { cvtpk(ps[0], ps[1]), cvtpk(ps[2], ps[3]),
                         cvtpk(ps[4], ps[5]), cvtpk(ps[6], ps[7]) };
      unsigned db[4] = { cvtpk(pd[0], pd[1]), cvtpk(pd[2], pd[3]),
                         cvtpk(pd[4], pd[5]), cvtpk(pd[6], pd[7]) };
      short8v as8 = *(const short8v*)da;   // A[m=l][k=s-32U] for K=32 PV
      short8v ad8 = *(const short8v*)db;

      __builtin_amdgcn_s_setprio(1);
      // denominator on the matrix pipe: acc_l[r] += sum_s pd[row=quad*4+r][s]
      acc_l = __builtin_amdgcn_mfma_f32_16x16x32_bf16(ad8, ones8, acc_l, 0, 0, 0);

      #pragma unroll
      for (int t = 0; t < 4; ++t) {
        short8v vf = *(const short8v*)(&vb_l[(t * 16 + ln15) * 64 +
                        (((4 * U + quad) ^ ln7) * 8)]);
        acc_s[t] = __builtin_amdgcn_mfma_f32_16x16x32_bf16(as8, vf, acc_s[t], 0, 0, 0);
        acc_d[t] = __builtin_amdgcn_mfma_f32_16x16x32_bf16(ad8, vf, acc_d[t], 0, 0, 0);
      }
      __builtin_amdgcn_s_setprio(0);
    }
  }

  // ---- combine the two s-streams (column-major scalar LDS, conflict-free) --
  __syncthreads();   // everyone done reading the last tiles -> ldsb reusable
  float* red = (float*)&ldsb[0][0][0];
  const int idx = ws * 64 + lane;        // same for partner waves strm 0/1
  if (strm == 1) {
    #pragma unroll
    for (int t = 0; t < 4; ++t)
      #pragma unroll
      for (int r = 0; r < 4; ++r) {
        red[(t * 4 + r) * 256 + idx]        = acc_s[t][r];
        red[(16 + t * 4 + r) * 256 + idx]   = acc_d[t][r];
      }
    #pragma unroll
    for (int r = 0; r < 4; ++r)
      red[(32 + r) * 256 + idx] = acc_l[r];
  }
  __syncthreads();
  if (strm == 0) {
    #pragma unroll
    for (int t = 0; t < 4; ++t)
      #pragma unroll
      for (int r = 0; r < 4; ++r) {
        acc_s[t][r] += red[(t * 4 + r) * 256 + idx];
        acc_d[t][r] += red[(16 + t * 4 + r) * 256 + idx];
      }
    #pragma unroll
    for (int r = 0; r < 4; ++r)
      acc_l[r] += red[(32 + r) * 256 + idx];

    const float w1 = __expf(a1p[0]), w2 = __expf(a2p[0]);
    // fold the (log2 e)^2 from the pre-scaled scores out of the sparse branch
    const float al1 = (w1 / (w1 + w2)) * 0.48045301391820142f; // (ln 2)^2
    const float al2 = w2 / (w1 + w2);

    float c_d[4];
    #pragma unroll
    for (int r = 0; r < 4; ++r) c_d[r] = al2 / acc_l[r];

    #pragma unroll
    for (int t = 0; t < 4; ++t) {
      #pragma unroll
      for (int r = 0; r < 4; ++r) {
        float val = al1 * acc_s[t][r] + c_d[r] * acc_d[t][r];
        const int l = lbase + quad * 4 + r;
        const int e = t * 16 + ln15;
        op[((size_t)(b * NL + l)) * HE + h * NE + e] = val;
      }
    }
  }
}

extern "C" void kernel_launch(void* const* d_in, const int* in_sizes, int n_in,
                              void* d_out, int out_size, void* d_ws, size_t ws_size,
                              hipStream_t stream) {
  const float* q  = (const float*)d_in[0];
  const float* k  = (const float*)d_in[1];
  const float* v  = (const float*)d_in[2];
  const float* a1 = (const float*)d_in[3];
  const float* a2 = (const float*)d_in[4];
  float* out = (float*)d_out;
  (void)in_sizes; (void)n_in; (void)out_size; (void)ws_size;

  u16* kimg = (u16*)d_ws;                                   // 4 MiB
  u16* vimg = kimg + (size_t)NB * NH * NST * TILE_U16;      // 4 MiB

  prepack<<<dim3(NB * NH * NST * 2), dim3(256), 0, stream>>>(k, v, kimg, vimg);
  assa_fwd<<<dim3(NB * NH * NLT), dim3(512), 0, stream>>>(q, kimg, vimg, a1, a2, out);
}